// Round 12
// baseline (290.228 us; speedup 1.0000x reference)
//
#include <hip/hip_runtime.h>
#include <hip/hip_bf16.h>

#define B_    64
#define S_    1024
#define CIN   5
#define K_    4
#define H1    64
#define H2    16
#define OUT_  32
#define L1_   1021      // S - K + 1
#define C1    22        // H2 + CIN + 1
#define C1SQ  484
#define SIGC1 506       // C1 + C1*C1
#define L2_   1018      // L1 - K + 1
#define SIGC2 272       // H2 + H2*H2
#define NCH   32        // sig2 time chunks
#define CH1   32        // sig2 steps per chunk

typedef __attribute__((ext_vector_type(8))) short short8;
typedef __attribute__((ext_vector_type(16))) float f32x16;

__device__ __forceinline__ unsigned short f2bf(float v) {
  __hip_bfloat16 h = __float2bfloat16(v);
  return *reinterpret_cast<unsigned short*>(&h);
}
__device__ __forceinline__ float bf2f(unsigned short u) {
  __hip_bfloat16 h;
  *reinterpret_cast<unsigned short*>(&h) = u;
  return __bfloat162float(h);
}

// ---------------- Kernel A: augment1 ----------
__global__ __launch_bounds__(256) void aug1_kernel(
    const float* __restrict__ x,
    const float* __restrict__ w0, const float* __restrict__ b0,
    const float* __restrict__ w1, const float* __restrict__ b1,
    const float* __restrict__ w2, const float* __restrict__ b2,
    float* __restrict__ h) {
  int b = blockIdx.y;
  int l = blockIdx.x * 256 + threadIdx.x;
  if (l >= L1_) return;
  const float* xb = x + (size_t)b * S_ * CIN;

  float t1[H1];
#pragma unroll
  for (int o = 0; o < H1; ++o) t1[o] = b0[o];
  for (int j = 0; j < K_; ++j) {
    for (int c = 0; c < CIN; ++c) {
      float xv = xb[(l + j) * CIN + c];
#pragma unroll
      for (int o = 0; o < H1; ++o) t1[o] += xv * w0[o * (CIN * K_) + c * K_ + j];
    }
  }
#pragma unroll
  for (int o = 0; o < H1; ++o) t1[o] = fmaxf(t1[o], 0.f);

  float t3[H2];
#pragma unroll
  for (int q = 0; q < H2; ++q) t3[q] = b2[q];
  for (int ch = 0; ch < 4; ++ch) {
    float t2c[16];
    for (int oc = 0; oc < 16; ++oc) {
      int o = ch * 16 + oc;
      float a = b1[o];
#pragma unroll
      for (int i = 0; i < H1; ++i) a += t1[i] * w1[o * H1 + i];
      t2c[oc] = fmaxf(a, 0.f);
    }
#pragma unroll
    for (int q = 0; q < H2; ++q) {
      float a = t3[q];
#pragma unroll
      for (int oc = 0; oc < 16; ++oc) a += t2c[oc] * w2[q * H1 + ch * 16 + oc];
      t3[q] = a;
    }
  }

  float* hr = h + ((size_t)b * L1_ + l) * C1;
#pragma unroll
  for (int c = 0; c < CIN; ++c) hr[c] = xb[(l + K_ - 1) * CIN + c];
  hr[CIN] = (float)l / (float)(L1_ - 1);
#pragma unroll
  for (int q = 0; q < H2; ++q) hr[CIN + 1 + q] = t3[q];
}

// ---------------- sig1a: per-(b, 128-row tile) chunk totals (tiles 0..6; tile 7 prefix unused) ------
__global__ __launch_bounds__(512) void sig1a_kernel(const float* __restrict__ h, float* __restrict__ tot1) {
  int kt = blockIdx.x, b = blockIdx.y;   // kt 0..6
  int tid = threadIdx.x;
  if (tid >= C1SQ) return;
  int start = kt * 128;
  const float* hb = h + (size_t)b * L1_ * C1;
  int i = tid / C1, j = tid - i * C1;
  float hpi = 0.f, hpj = 0.f;
  if (kt > 0) {
    hpi = hb[(start - 1) * C1 + i];
    hpj = hb[(start - 1) * C1 + j];
  }
  float pi = 0.f, pj = 0.f, s2 = 0.f;
#pragma unroll 4
  for (int t = start; t < start + 128; ++t) {
    float ci = hb[t * C1 + i] - hpi;
    float cj = hb[t * C1 + j] - hpj;
    float dj = cj - pj;
    s2 += pi * dj + 0.5f * (ci - pi) * dj;
    pi = ci;
    pj = cj;
  }
  tot1[((size_t)b * 8 + kt) * C1SQ + tid] = s2;
}

// ---------------- Kernel W2: pack a2_w0 into B-fragment order, bf16 hi/lo ---------------------------
__global__ __launch_bounds__(256) void wt2_kernel(const float* __restrict__ w0,
                                                  unsigned short* __restrict__ bhi,
                                                  unsigned short* __restrict__ blo) {
  int idx = blockIdx.x * 256 + threadIdx.x;
  if (idx >= 2 * 128 * 64 * 8) return;
  int e = idx & 7;
  int lane = (idx >> 3) & 63;
  int ksg = (idx >> 9) & 127;
  int ot = idx >> 16;
  int j = ksg >> 5, cc = (ksg >> 2) & 7, ks = ksg & 3;
  int o = ot * 32 + (lane & 31);
  int c = cc * 64 + ks * 16 + (lane >> 5) * 8 + e;
  float v = (c < SIGC1) ? w0[o * (SIGC1 * K_) + c * K_ + j] : 0.f;
  unsigned short hb16 = f2bf(v);
  bhi[idx] = hb16;
  blo[idx] = f2bf(v - bf2f(hb16));
}

// ---------------- Kernel C: fused sig1-stream + MFMA conv + pointwise convs -> h2 -------------------
// M=128 tile per block (grid 8 x B). A double-buffered: generate chunk cc into buf cc&1 while the
// matrix pipe drains MFMA(cc-1) from the other buffer. B staged early each chunk (latency under gen).
// LDS (K-loop):  hs f32[137][22] @0 (12056->12288) | Abuf 2x(Ah 17408 + Al 17408) @12288..81920 |
//                Bs @81920 (65536) | gsum [8][64] @147456 | s2pl [484] @149504 -> 151440
// LDS (epilogue, reuse): t1s f32[128][65] @0 | t2s @33280 | wl @66560 (20KB) -> 87040
__global__ __launch_bounds__(512) void conv2pw_kernel(
    const float* __restrict__ h, const float* __restrict__ tot1,
    const unsigned short* __restrict__ bpkhi, const unsigned short* __restrict__ bpklo,
    const float* __restrict__ b0,
    const float* __restrict__ w1, const float* __restrict__ b1,
    const float* __restrict__ w2, const float* __restrict__ b2,
    float* __restrict__ h2) {
  __shared__ __align__(16) char smem[151552];
  int tid = threadIdx.x;
  int lane = tid & 63, w = tid >> 6;   // w = time-group for generation
  int wm = w >> 1, wo = w & 1;         // MFMA: wm = 32-row tile (0..3), wo = 32-col half
  int k = blockIdx.x, b = blockIdx.y, l0 = k * 128;
  const float* hb = h + (size_t)b * L1_ * C1;
  const char* bhg = (const char*)bpkhi;
  const char* blg = (const char*)bpklo;
  float* hs = (float*)smem;                       // [137][22]
  char* Abuf = smem + 12288;
  char* Bs = smem + 81920;
  float* gsum = (float*)(smem + 147456);          // [8][64]
  float* s2pl = (float*)(smem + 149504);          // [484]

  // ---- prologue: stage h rows l0-1 .. l0+135 (clamped; row 0 = basepoint for k=0) ----
  for (int idx = tid; idx < 137 * C1; idx += 512) {
    int r = idx / C1, c = idx - r * C1;
    float v = 0.f;
    if (!(k == 0 && r == 0)) {
      int hr = l0 - 1 + r;
      if (hr > L1_ - 1) hr = L1_ - 1;
      v = hb[hr * C1 + c];
    }
    hs[idx] = v;
  }
  // ---- per-channel tile prefix via Chen over preceding 128-row tiles ----
  if (tid < C1SQ) {
    int i = tid / C1, j = tid - i * C1;
    float s2pv = 0.f;
    for (int kp = 0; kp < k; ++kp) {
      float bvi = 0.f, bvj = 0.f;
      if (kp > 0) {
        bvi = hb[(128 * kp - 1) * C1 + i];
        bvj = hb[(128 * kp - 1) * C1 + j];
      }
      float bv1j = hb[(128 * (kp + 1) - 1) * C1 + j];
      s2pv += bvi * (bv1j - bvj) + tot1[((size_t)b * 8 + kp) * C1SQ + tid];
    }
    s2pl[tid] = s2pv;
  }
  __syncthreads();

  f32x16 aHH = {}, aHL = {}, aLH = {};
  int khalf = lane >> 5;
  int r0 = 32 * wm + (lane & 31);

  for (int cc = 0; cc < 8; ++cc) {
    if (cc) __syncthreads();   // prior MFMA's Bs/A ds_reads complete before restage
    // ---- stage B(cc) early: 64 x 1KB segments (latency hides under generation) ----
    for (int s = w; s < 64; s += 8) {
      int p = s >> 2, ot = (s >> 1) & 1, plane = s & 1;
      int jj = p >> 2, ks = p & 3;
      int ksg = jj * 32 + cc * 4 + ks;
      const char* src = (plane ? blg : bhg) + (size_t)(ot * 128 + ksg) * 1024 + lane * 16;
      __builtin_amdgcn_global_load_lds(
          (const __attribute__((address_space(1))) void*)src,
          (__attribute__((address_space(3))) void*)(Bs + ((p * 2 + ot) * 2 + plane) * 1024), 16, 0, 0);
    }
    char* Ah = Abuf + (cc & 1) * 34816;
    char* Al = Ah + 17408;
    // ---- generate A(cc) into buf cc&1: channel c = cc*64+lane, group w: rows u0..u0+16 ----
    int c = cc * 64 + lane;
    bool isS2 = (c >= C1 && c < SIGC1);
    int ii = 0, jj2 = 0;
    if (isS2) {
      int idx = c - C1;
      ii = idx / C1;
      jj2 = idx - ii * C1;
    }
    float hpi = hs[ii], hpj = hs[jj2];
    int u0 = w * 17;
    {  // phase 1: group partial depth-2 sum
      float pi = hs[u0 * C1 + ii] - hpi;
      float pj = hs[u0 * C1 + jj2] - hpj;
      float loc = 0.f;
      for (int s = 0; s < 17; ++s) {
        int u = u0 + s;
        float ci = hs[(u + 1) * C1 + ii] - hpi;
        float cj = hs[(u + 1) * C1 + jj2] - hpj;
        float dj = cj - pj;
        loc += pi * dj + 0.5f * (ci - pi) * dj;
        pi = ci;
        pj = cj;
      }
      gsum[w * 64 + lane] = loc;
    }
    __syncthreads();
    {  // phase 2: group-prefix + re-scan, emit bf16 hi/lo into swizzled LDS
      float s2r = isS2 ? s2pl[c - C1] : 0.f;
      for (int gp = 0; gp < w; ++gp) s2r += gsum[gp * 64 + lane];
      float pi = hs[u0 * C1 + ii] - hpi;
      float pj = hs[u0 * C1 + jj2] - hpj;
      for (int s = 0; s < 17; ++s) {
        int u = u0 + s;
        float v;
        if (isS2) {
          float ci = hs[(u + 1) * C1 + ii] - hpi;
          float cj = hs[(u + 1) * C1 + jj2] - hpj;
          float dj = cj - pj;
          s2r += pi * dj + 0.5f * (ci - pi) * dj;
          pi = ci;
          pj = cj;
          v = s2r + hpi * cj;                 // Chen: A2 + A1 (x) B1 + B2
        } else if (c < C1) {
          v = hs[(u + 1) * C1 + c];           // level 1 = unshifted h[t]
        } else {
          v = 0.f;                            // pad channels 506..511
        }
        unsigned short hb16 = f2bf(v);
        unsigned short lb16 = f2bf(v - bf2f(hb16));
        int boff = u * 128 + (((lane >> 3) ^ (u & 7)) << 4) + (lane & 7) * 2;
        *(unsigned short*)(Ah + boff) = hb16;
        *(unsigned short*)(Al + boff) = lb16;
      }
    }
    __syncthreads();   // A(cc) visible; vmcnt drained -> B(cc) ready
    // ---- MFMA(cc): executes in matrix pipe overlapping next chunk's generation VALU ----
#pragma unroll
    for (int j = 0; j < 4; ++j) {
      int ra = r0 + j;
      int rx = ra & 7;
      const char* ab = Ah + ra * 128;
      const char* abl = Al + ra * 128;
#pragma unroll
      for (int ks = 0; ks < 4; ++ks) {
        int p = j * 4 + ks;
        const char* bb = Bs + (size_t)((p * 2 + wo) * 2) * 1024 + lane * 16;
        short8 b_h = *(const short8*)bb;
        short8 b_l = *(const short8*)(bb + 1024);
        int g0 = ((ks * 2 + khalf) ^ rx) << 4;
        short8 vh = *(const short8*)(ab + g0);
        short8 vl = *(const short8*)(abl + g0);
        aHH = __builtin_amdgcn_mfma_f32_32x32x16_bf16(vh, b_h, aHH, 0, 0, 0);
        aHL = __builtin_amdgcn_mfma_f32_32x32x16_bf16(vh, b_l, aHL, 0, 0, 0);
        aLH = __builtin_amdgcn_mfma_f32_32x32x16_bf16(vl, b_h, aLH, 0, 0, 0);
      }
    }
  }
  __syncthreads();
  // ---- epilogue: relu(t1+b0) -> 1x1(64->64)+relu -> 1x1(64->16) -> h2 ----
  float* t1s = (float*)smem;                  // [128][65]
  float* t2s = (float*)(smem + 33280);        // [128][65]
  float* wl = (float*)(smem + 66560);         // w1 4096 f, w2 1024 f
  for (int i2 = tid; i2 < 4096; i2 += 512) wl[i2] = w1[i2];
  for (int i2 = tid; i2 < 1024; i2 += 512) wl[4096 + i2] = w2[i2];
  {
    int col = 32 * wo + (lane & 31);
    float bbv = b0[col];
    int rbase = 32 * wm + 4 * khalf;
#pragma unroll
    for (int rg = 0; rg < 16; ++rg) {
      int row = (rg & 3) + 8 * (rg >> 2) + rbase;
      t1s[row * 65 + col] = fmaxf(aHH[rg] + aHL[rg] + aLH[rg] + bbv, 0.f);
    }
  }
  __syncthreads();
  {  // 1x1 (64->64) + relu ; thread = (row, quarter)
    int row = tid >> 2, q = tid & 3;
    const float* trow = t1s + row * 65;
    float tr[64];
#pragma unroll
    for (int i2 = 0; i2 < 64; ++i2) tr[i2] = trow[i2];
#pragma unroll
    for (int oc = 0; oc < 16; ++oc) {
      int o = q * 16 + oc;
      float a = b1[o];
      const float4* wr = (const float4*)(wl + o * 64);
#pragma unroll
      for (int i4 = 0; i4 < 16; ++i4) {
        float4 wv = wr[i4];
        a += tr[i4 * 4] * wv.x + tr[i4 * 4 + 1] * wv.y +
             tr[i4 * 4 + 2] * wv.z + tr[i4 * 4 + 3] * wv.w;
      }
      t2s[row * 65 + o] = fmaxf(a, 0.f);
    }
  }
  __syncthreads();
  {  // 1x1 (64->16) -> h2 ; thread = (row, p-quarter)
    int row = tid >> 2, pg = tid & 3;
    int l = l0 + row;
    if (l < L2_) {
      const float* trow = t2s + row * 65;
      float tr2[64];
#pragma unroll
      for (int i2 = 0; i2 < 64; ++i2) tr2[i2] = trow[i2];
      float* outr = h2 + ((size_t)b * L2_ + l) * H2;
#pragma unroll
      for (int pp = 0; pp < 4; ++pp) {
        int pch = pg * 4 + pp;
        float a = b2[pch];
        const float4* wr = (const float4*)(wl + 4096 + pch * 64);
#pragma unroll
        for (int i4 = 0; i4 < 16; ++i4) {
          float4 wv = wr[i4];
          a += tr2[i4 * 4] * wv.x + tr2[i4 * 4 + 1] * wv.y +
               tr2[i4 * 4 + 2] * wv.z + tr2[i4 * 4 + 3] * wv.w;
        }
        outr[pch] = a;
      }
    }
  }
}

// ---------------- sig2 phase A: de-barriered per-(b,chunk) scan with become_constant clamp ----------
__global__ __launch_bounds__(256) void sig2a_kernel(const float* __restrict__ h2, const int* __restrict__ lengths,
                                                    float* __restrict__ s2tot2) {
  int k = blockIdx.x, b = blockIdx.y;
  int tid = threadIdx.x;
  int i = tid >> 4, j = tid & 15;
  int adjm1 = lengths[b] - (2 * K_ - 2) - 1;  // lengths - 7
  int start = k * CH1, end = min(start + CH1 - 1, L2_ - 1);
  size_t oidx = ((size_t)b * NCH + k) * 256 + tid;
  if (k > 0 && start - 1 >= adjm1) {
    s2tot2[oidx] = 0.f;
    return;
  }
  const float* h2b = h2 + (size_t)b * L2_ * H2;
  float hpi = 0.f, hpj = 0.f;
  if (k > 0) {
    int row = min(start - 1, adjm1);
    hpi = h2b[row * H2 + i];
    hpj = h2b[row * H2 + j];
  }
  float pi = 0.f, pj = 0.f, s2 = 0.f;
#pragma unroll 4
  for (int t = start; t <= end; ++t) {
    int row = min(t, adjm1);
    float ci = h2b[row * H2 + i] - hpi;
    float cj = h2b[row * H2 + j] - hpj;
    float dj = cj - pj;
    s2 += pi * dj + 0.5f * (ci - pi) * dj;
    pi = ci;
    pj = cj;
  }
  s2tot2[oidx] = s2;
}

// ---------------- sig2 phase B: NCH-step Chen combine + final linear -----------------
__global__ __launch_bounds__(256) void sig2b_kernel(const float* __restrict__ h2, const int* __restrict__ lengths,
                                                    const float* __restrict__ s2tot2,
                                                    const float* __restrict__ lin_w, const float* __restrict__ lin_b,
                                                    float* __restrict__ out) {
  int b = blockIdx.x;
  int tid = threadIdx.x;
  int i = tid >> 4, j = tid & 15;
  int adjm1 = lengths[b] - (2 * K_ - 2) - 1;
  const float* h2b = h2 + (size_t)b * L2_ * H2;
  __shared__ float bv[NCH + 1][H2];
  __shared__ float s2s[SIGC2];
  for (int idx = tid; idx < (NCH + 1) * H2; idx += 256) {
    int kk = idx >> 4, c = idx & 15;
    float v = 0.f;
    if (kk > 0) {
      int row = min(min(CH1 * kk - 1, L2_ - 1), adjm1);
      v = h2b[row * H2 + c];
    }
    bv[kk][c] = v;
  }
  __syncthreads();
  float s2 = 0.f;
  for (int k = 0; k < NCH; ++k) {
    s2 += bv[k][i] * (bv[k + 1][j] - bv[k][j]) + s2tot2[((size_t)b * NCH + k) * 256 + tid];
  }
  s2s[H2 + tid] = s2;
  if (tid < H2) s2s[tid] = bv[NCH][tid];
  __syncthreads();
  if (tid < OUT_) {
    float a = lin_b[tid];
    for (int c = 0; c < SIGC2; ++c) a += s2s[c] * lin_w[tid * SIGC2 + c];
    out[b * OUT_ + tid] = a;
  }
}

extern "C" void kernel_launch(void* const* d_in, const int* in_sizes, int n_in,
                              void* d_out, int out_size, void* d_ws, size_t ws_size,
                              hipStream_t stream) {
  const float* x      = (const float*)d_in[0];
  const int*   lengths= (const int*)d_in[1];
  const float* a1_w0  = (const float*)d_in[2];
  const float* a1_b0  = (const float*)d_in[3];
  const float* a1_w1  = (const float*)d_in[4];
  const float* a1_b1  = (const float*)d_in[5];
  const float* a1_w2  = (const float*)d_in[6];
  const float* a1_b2  = (const float*)d_in[7];
  const float* a2_w0  = (const float*)d_in[8];
  const float* a2_b0  = (const float*)d_in[9];
  const float* a2_w1  = (const float*)d_in[10];
  const float* a2_b1  = (const float*)d_in[11];
  const float* a2_w2  = (const float*)d_in[12];
  const float* a2_b2  = (const float*)d_in[13];
  const float* lin_w  = (const float*)d_in[14];
  const float* lin_b  = (const float*)d_in[15];
  float* outp = (float*)d_out;

  float* ws = (float*)d_ws;
  // layout (float offsets):
  float* h = ws;                                            // 1,437,568 f
  unsigned short* bpkhi = (unsigned short*)(ws + 1437568);  // 131,072 u16
  unsigned short* bpklo = bpkhi + 131072;
  float* h2 = ws + 1568640;                                 // 1,042,432 f
  float* tot1 = ws + 2611072;                               // B*8*C1SQ = 247,808 f
  float* s2tot2 = ws + 2858880;                             // B*NCH*256 = 524,288 f -> 3,383,168 f (13.5 MB)

  aug1_kernel<<<dim3(4, B_), 256, 0, stream>>>(x, a1_w0, a1_b0, a1_w1, a1_b1, a1_w2, a1_b2, h);
  wt2_kernel<<<(2 * 128 * 64 * 8 + 255) / 256, 256, 0, stream>>>(a2_w0, bpkhi, bpklo);
  sig1a_kernel<<<dim3(7, B_), 512, 0, stream>>>(h, tot1);
  conv2pw_kernel<<<dim3(8, B_), 512, 0, stream>>>(h, tot1, bpkhi, bpklo, a2_b0,
                                                  a2_w1, a2_b1, a2_w2, a2_b2, h2);
  sig2a_kernel<<<dim3(NCH, B_), 256, 0, stream>>>(h2, lengths, s2tot2);
  sig2b_kernel<<<B_, 256, 0, stream>>>(h2, lengths, s2tot2, lin_w, lin_b, outp);
}